// Round 4
// baseline (460.475 us; speedup 1.0000x reference)
//
#include <hip/hip_runtime.h>
#include <hip/hip_bf16.h>

static constexpr int VN = 500000;   // nodes
static constexpr int DD = 128;      // feature dim
static constexpr int NE = 1000000;  // hyperedges
static constexpr int KE = 8;        // nodes per hyperedge
static constexpr int CC = 16;       // layer-3 width
static constexpr int H1 = 8;        // hidden width
static constexpr int NB = (VN + 255) / 256;  // 1954 scan blocks

typedef float fvec4 __attribute__((ext_vector_type(4)));

// Fused: cnt[v]=0 ; proj[v] = X[v,:]·rv ; A[v,0:8] = X[v,:]·W1 (RS=8)
__global__ __launch_bounds__(256) void k_row(const float* __restrict__ X,
                                             const float* __restrict__ rv,
                                             const float* __restrict__ W1,
                                             float* __restrict__ proj,
                                             float* __restrict__ A,
                                             int* __restrict__ cnt) {
    int v = blockIdx.x * 256 + threadIdx.x;
    if (v >= VN) return;
    cnt[v] = 0;
    const fvec4* xr = reinterpret_cast<const fvec4*>(X + (size_t)v * DD);
    const float4* rr = reinterpret_cast<const float4*>(rv);
    float accP = 0.f;
    float accM[H1];
#pragma unroll
    for (int j = 0; j < H1; ++j) accM[j] = 0.f;
#pragma unroll 8
    for (int k = 0; k < DD / 4; ++k) {
        fvec4 x = __builtin_nontemporal_load(&xr[k]);
        float4 r = rr[k];
        accP += x.x * r.x + x.y * r.y + x.z * r.z + x.w * r.w;
#pragma unroll
        for (int q = 0; q < 4; ++q) {
            float xv = (q == 0) ? x.x : (q == 1) ? x.y : (q == 2) ? x.z : x.w;
            const float4 wa = *reinterpret_cast<const float4*>(W1 + (size_t)(k * 4 + q) * H1);
            const float4 wb = *reinterpret_cast<const float4*>(W1 + (size_t)(k * 4 + q) * H1 + 4);
            accM[0] += xv * wa.x; accM[1] += xv * wa.y;
            accM[2] += xv * wa.z; accM[3] += xv * wa.w;
            accM[4] += xv * wb.x; accM[5] += xv * wb.y;
            accM[6] += xv * wb.z; accM[7] += xv * wb.w;
        }
    }
    proj[v] = accP;
    float4* a4 = reinterpret_cast<float4*>(A + (size_t)v * H1);
    a4[0] = make_float4(accM[0], accM[1], accM[2], accM[3]);
    a4[1] = make_float4(accM[4], accM[5], accM[6], accM[7]);
}

// Per-edge argmax/argmin of proj (first occurrence wins); packed int2 store;
// count incident entries per node.
__global__ __launch_bounds__(256) void k_edge(const int* __restrict__ E,
                                              const float* __restrict__ proj,
                                              int2* __restrict__ SI,
                                              int* __restrict__ cnt) {
    int e = blockIdx.x * 256 + threadIdx.x;
    if (e >= NE) return;
    const int* er = E + (size_t)e * KE;
    int4 e0 = *reinterpret_cast<const int4*>(er);
    int4 e1 = *reinterpret_cast<const int4*>(er + 4);
    int ids[KE] = {e0.x, e0.y, e0.z, e0.w, e1.x, e1.y, e1.z, e1.w};
    float p[KE];
#pragma unroll
    for (int j = 0; j < KE; ++j) p[j] = proj[ids[j]];
    float bestMax = p[0], bestMin = p[0];
    int idMax = ids[0], idMin = ids[0];
#pragma unroll
    for (int j = 1; j < KE; ++j) {
        if (p[j] > bestMax) { bestMax = p[j]; idMax = ids[j]; }
        if (p[j] < bestMin) { bestMin = p[j]; idMin = ids[j]; }
    }
    SI[e] = make_int2(idMax, idMin);
    atomicAdd(cnt + idMax, 1);
    atomicAdd(cnt + idMin, 1);
}

// scan step 1: per-block sums of cnt
__global__ __launch_bounds__(256) void k_scan1(const int* __restrict__ cnt,
                                               int* __restrict__ bsum) {
    __shared__ int sm[256];
    int v = blockIdx.x * 256 + threadIdx.x;
    sm[threadIdx.x] = (v < VN) ? cnt[v] : 0;
    __syncthreads();
    for (int s = 128; s > 0; s >>= 1) {
        if (threadIdx.x < s) sm[threadIdx.x] += sm[threadIdx.x + s];
        __syncthreads();
    }
    if (threadIdx.x == 0) bsum[blockIdx.x] = sm[0];
}

// scan step 2: exclusive scan of block sums (single block, chunked)
__global__ __launch_bounds__(256) void k_scan2(int* __restrict__ bsum, int nb) {
    __shared__ int sm[256];
    __shared__ int carry;
    if (threadIdx.x == 0) carry = 0;
    __syncthreads();
    for (int base = 0; base < nb; base += 256) {
        int i = base + threadIdx.x;
        int x = (i < nb) ? bsum[i] : 0;
        sm[threadIdx.x] = x;
        __syncthreads();
        for (int off = 1; off < 256; off <<= 1) {
            int t = (threadIdx.x >= off) ? sm[threadIdx.x - off] : 0;
            __syncthreads();
            sm[threadIdx.x] += t;
            __syncthreads();
        }
        int excl = sm[threadIdx.x] - x;
        if (i < nb) bsum[i] = excl + carry;
        __syncthreads();
        if (threadIdx.x == 0) carry += sm[255];
        __syncthreads();
    }
}

// scan step 3 (fused seed): rowptr, fill=0, dinv, A *= dinv
__global__ __launch_bounds__(256) void k_scan3(const int* __restrict__ cnt,
                                               const int* __restrict__ bsum,
                                               int* __restrict__ rowptr,
                                               int* __restrict__ fill,
                                               float* __restrict__ dinv,
                                               float* __restrict__ A) {
    __shared__ int sm[256];
    int v = blockIdx.x * 256 + threadIdx.x;
    int x = (v < VN) ? cnt[v] : 0;
    sm[threadIdx.x] = x;
    __syncthreads();
    for (int off = 1; off < 256; off <<= 1) {
        int t = (threadIdx.x >= off) ? sm[threadIdx.x - off] : 0;
        __syncthreads();
        sm[threadIdx.x] += t;
        __syncthreads();
    }
    int excl = sm[threadIdx.x] - x + bsum[blockIdx.x];
    if (v < VN) {
        rowptr[v] = excl;
        fill[v] = 0;
        float di = rsqrtf(1.0f + 0.125f * (float)x);
        dinv[v] = di;
        float4* ar = reinterpret_cast<float4*>(A + (size_t)v * H1);
        float4 a0 = ar[0], a1 = ar[1];
        ar[0] = make_float4(di * a0.x, di * a0.y, di * a0.z, di * a0.w);
        ar[1] = make_float4(di * a1.x, di * a1.y, di * a1.z, di * a1.w);
    }
    if (v == VN - 1) rowptr[VN] = excl + x;
}

// fill CSR columns (slot via atomic)
__global__ __launch_bounds__(256) void k_fill(const int2* __restrict__ SI,
                                              const int* __restrict__ rowptr,
                                              int* __restrict__ fill,
                                              int* __restrict__ colv) {
    int e = blockIdx.x * 256 + threadIdx.x;
    if (e >= NE) return;
    int2 si = SI[e];
    int ps = atomicAdd(fill + si.x, 1);
    colv[rowptr[si.x] + ps] = si.y;
    int pi = atomicAdd(fill + si.y, 1);
    colv[rowptr[si.y] + pi] = si.x;
}

// Gather SpMM + bias + ReLU + tiny matmul; Min rows RSI floats, Mout RSO.
// Y[v] = dinv[v]*(M'[v] + 0.125*sum_c M'[c]);  Mout = dinv * (relu(Y+b) @ W)
template <int FIN, int FOUT, int RSI, int RSO>
__global__ __launch_bounds__(256) void k_glayer(const int* __restrict__ rowptr,
                                                const int* __restrict__ colv,
                                                const float* __restrict__ dinv,
                                                const float* __restrict__ bias,
                                                const float* __restrict__ W,
                                                const float* __restrict__ Min,
                                                float* __restrict__ Mout) {
    int v = blockIdx.x * 256 + threadIdx.x;
    if (v >= VN) return;
    float own[FIN], s[FIN];
    const float4* mr = reinterpret_cast<const float4*>(Min + (size_t)v * RSI);
#pragma unroll
    for (int j = 0; j < FIN / 4; ++j) {
        float4 t = mr[j];
        own[4 * j] = t.x; own[4 * j + 1] = t.y;
        own[4 * j + 2] = t.z; own[4 * j + 3] = t.w;
    }
#pragma unroll
    for (int j = 0; j < FIN; ++j) s[j] = 0.f;
    int p = rowptr[v], end = rowptr[v + 1];
    // chunk-of-4 pipelined gather: 4 colv loads, then 4*FIN/4 row loads in flight
    for (; p + 4 <= end; p += 4) {
        int c0 = colv[p], c1 = colv[p + 1], c2 = colv[p + 2], c3 = colv[p + 3];
        const float4* r0 = reinterpret_cast<const float4*>(Min + (size_t)c0 * RSI);
        const float4* r1 = reinterpret_cast<const float4*>(Min + (size_t)c1 * RSI);
        const float4* r2 = reinterpret_cast<const float4*>(Min + (size_t)c2 * RSI);
        const float4* r3 = reinterpret_cast<const float4*>(Min + (size_t)c3 * RSI);
        float4 t0[FIN / 4], t1[FIN / 4], t2[FIN / 4], t3[FIN / 4];
#pragma unroll
        for (int j = 0; j < FIN / 4; ++j) t0[j] = r0[j];
#pragma unroll
        for (int j = 0; j < FIN / 4; ++j) t1[j] = r1[j];
#pragma unroll
        for (int j = 0; j < FIN / 4; ++j) t2[j] = r2[j];
#pragma unroll
        for (int j = 0; j < FIN / 4; ++j) t3[j] = r3[j];
#pragma unroll
        for (int j = 0; j < FIN / 4; ++j) {
            s[4 * j]     += t0[j].x + t1[j].x + t2[j].x + t3[j].x;
            s[4 * j + 1] += t0[j].y + t1[j].y + t2[j].y + t3[j].y;
            s[4 * j + 2] += t0[j].z + t1[j].z + t2[j].z + t3[j].z;
            s[4 * j + 3] += t0[j].w + t1[j].w + t2[j].w + t3[j].w;
        }
    }
    for (; p < end; ++p) {
        int c = colv[p];
        const float4* cr = reinterpret_cast<const float4*>(Min + (size_t)c * RSI);
#pragma unroll
        for (int j = 0; j < FIN / 4; ++j) {
            float4 t = cr[j];
            s[4 * j] += t.x; s[4 * j + 1] += t.y;
            s[4 * j + 2] += t.z; s[4 * j + 3] += t.w;
        }
    }
    float di = dinv[v];
    float h[FIN];
#pragma unroll
    for (int j = 0; j < FIN; ++j) {
        float y = di * (own[j] + 0.125f * s[j]) + bias[j];
        h[j] = y > 0.f ? y : 0.f;
    }
#pragma unroll
    for (int c = 0; c < FOUT; ++c) {
        float m = 0.f;
#pragma unroll
        for (int j = 0; j < FIN; ++j) m += h[j] * W[j * FOUT + c];
        Mout[(size_t)v * RSO + c] = di * m;
    }
}

// Final: gather Y3 (rows RS=16), relu(Y3+b3), dot fc_w, sigmoid
__global__ __launch_bounds__(256) void k_gfinal(const int* __restrict__ rowptr,
                                                const int* __restrict__ colv,
                                                const float* __restrict__ dinv,
                                                const float* __restrict__ b3,
                                                const float* __restrict__ fcw,
                                                const float* __restrict__ fcb,
                                                const float* __restrict__ Min,
                                                float* __restrict__ out) {
    int v = blockIdx.x * 256 + threadIdx.x;
    if (v >= VN) return;
    float own[CC], s[CC];
    const float4* mr = reinterpret_cast<const float4*>(Min + (size_t)v * CC);
#pragma unroll
    for (int j = 0; j < CC / 4; ++j) {
        float4 t = mr[j];
        own[4 * j] = t.x; own[4 * j + 1] = t.y;
        own[4 * j + 2] = t.z; own[4 * j + 3] = t.w;
    }
#pragma unroll
    for (int j = 0; j < CC; ++j) s[j] = 0.f;
    int p = rowptr[v], end = rowptr[v + 1];
    // chunk-of-2 pipelined gather (2 * 4 float4 loads in flight)
    for (; p + 2 <= end; p += 2) {
        int c0 = colv[p], c1 = colv[p + 1];
        const float4* r0 = reinterpret_cast<const float4*>(Min + (size_t)c0 * CC);
        const float4* r1 = reinterpret_cast<const float4*>(Min + (size_t)c1 * CC);
        float4 t0[CC / 4], t1[CC / 4];
#pragma unroll
        for (int j = 0; j < CC / 4; ++j) t0[j] = r0[j];
#pragma unroll
        for (int j = 0; j < CC / 4; ++j) t1[j] = r1[j];
#pragma unroll
        for (int j = 0; j < CC / 4; ++j) {
            s[4 * j]     += t0[j].x + t1[j].x;
            s[4 * j + 1] += t0[j].y + t1[j].y;
            s[4 * j + 2] += t0[j].z + t1[j].z;
            s[4 * j + 3] += t0[j].w + t1[j].w;
        }
    }
    for (; p < end; ++p) {
        int c = colv[p];
        const float4* cr = reinterpret_cast<const float4*>(Min + (size_t)c * CC);
#pragma unroll
        for (int j = 0; j < CC / 4; ++j) {
            float4 t = cr[j];
            s[4 * j] += t.x; s[4 * j + 1] += t.y;
            s[4 * j + 2] += t.z; s[4 * j + 3] += t.w;
        }
    }
    float di = dinv[v];
    float acc = fcb[0];
#pragma unroll
    for (int j = 0; j < CC; ++j) {
        float y = di * (own[j] + 0.125f * s[j]) + b3[j];
        float hh = y > 0.f ? y : 0.f;
        acc += hh * fcw[j];
    }
    out[v] = 1.f / (1.f + expf(-acc));
}

extern "C" void kernel_launch(void* const* d_in, const int* in_sizes, int n_in,
                              void* d_out, int out_size, void* d_ws, size_t ws_size,
                              hipStream_t stream) {
    const float* X   = (const float*)d_in[0];
    const int*   E   = (const int*)d_in[1];
    const float* rv  = (const float*)d_in[2];
    const float* W1  = (const float*)d_in[3];
    const float* b1  = (const float*)d_in[4];
    const float* W2  = (const float*)d_in[5];
    const float* b2  = (const float*)d_in[6];
    const float* W3  = (const float*)d_in[7];
    const float* b3  = (const float*)d_in[8];
    const float* fcw = (const float*)d_in[9];
    const float* fcb = (const float*)d_in[10];
    float* out = (float*)d_out;

    float* ws = (float*)d_ws;
    float* A    = ws;                          // [VN x 8]  16 MB (M1')
    float* B    = ws + 4000000;                // [VN x 8]  16 MB (M2')
    float* C    = ws + 8000000;                // [VN x 16] 32 MB (M3')
    float* proj = ws + 16000000;               // [VN]
    float* dinv = ws + 16500000;               // [VN]
    int*   cnt  = (int*)(ws + 17000000);       // [VN]
    int*   rowptr = (int*)(ws + 17500000);     // [VN+1]
    int*   fill = (int*)(ws + 18001000);       // [VN]
    int*   bsum = (int*)(ws + 18501000);       // [NB]
    int2*  SI   = (int2*)(ws + 18503000);      // [NE] packed (Se,Ie)
    int*   colv = (int*)(ws + 20503000);       // [2*NE]

    dim3 blk(256);
    int gV = (VN + 255) / 256;   // = NB
    int gE = (NE + 255) / 256;

    k_row<<<gV, blk, 0, stream>>>(X, rv, W1, proj, A, cnt);
    k_edge<<<gE, blk, 0, stream>>>(E, proj, SI, cnt);
    k_scan1<<<gV, blk, 0, stream>>>(cnt, bsum);
    k_scan2<<<1, blk, 0, stream>>>(bsum, NB);
    k_scan3<<<gV, blk, 0, stream>>>(cnt, bsum, rowptr, fill, dinv, A);
    k_fill<<<gE, blk, 0, stream>>>(SI, rowptr, fill, colv);

    // layer 1: A(M1',RS8) -> B(M2',RS8)
    k_glayer<8, 8, 8, 8><<<gV, blk, 0, stream>>>(rowptr, colv, dinv, b1, W2, A, B);
    // layer 2: B(M2',RS8) -> C(M3',RS16)
    k_glayer<8, 16, 8, 16><<<gV, blk, 0, stream>>>(rowptr, colv, dinv, b2, W3, B, C);
    // layer 3 + head: C(M3',RS16) -> out
    k_gfinal<<<gV, blk, 0, stream>>>(rowptr, colv, dinv, b3, fcw, fcb, C, out);
}

// Round 5
// 374.859 us; speedup vs baseline: 1.2284x; 1.2284x over previous
//
#include <hip/hip_runtime.h>
#include <hip/hip_bf16.h>

static constexpr int VN = 500000;   // nodes
static constexpr int DD = 128;      // feature dim
static constexpr int NE = 1000000;  // hyperedges
static constexpr int KE = 8;        // nodes per hyperedge
static constexpr int CC = 16;       // layer-3 width
static constexpr int H1 = 8;        // hidden width
static constexpr int EW = 64;       // ELL width (P[Poisson(16) >= 64] ~ 1e-18)

typedef float fvec4 __attribute__((ext_vector_type(4)));

// Fused: fill[v]=0 ; proj[v] = X[v,:]·rv ; A[v,0:8] = X[v,:]·W1
__global__ __launch_bounds__(256) void k_row(const float* __restrict__ X,
                                             const float* __restrict__ rv,
                                             const float* __restrict__ W1,
                                             float* __restrict__ proj,
                                             float* __restrict__ A,
                                             int* __restrict__ fill) {
    int v = blockIdx.x * 256 + threadIdx.x;
    if (v >= VN) return;
    fill[v] = 0;
    const fvec4* xr = reinterpret_cast<const fvec4*>(X + (size_t)v * DD);
    const float4* rr = reinterpret_cast<const float4*>(rv);
    float accP = 0.f;
    float accM[H1];
#pragma unroll
    for (int j = 0; j < H1; ++j) accM[j] = 0.f;
#pragma unroll 8
    for (int k = 0; k < DD / 4; ++k) {
        fvec4 x = __builtin_nontemporal_load(&xr[k]);
        float4 r = rr[k];
        accP += x.x * r.x + x.y * r.y + x.z * r.z + x.w * r.w;
#pragma unroll
        for (int q = 0; q < 4; ++q) {
            float xv = (q == 0) ? x.x : (q == 1) ? x.y : (q == 2) ? x.z : x.w;
            const float4 wa = *reinterpret_cast<const float4*>(W1 + (size_t)(k * 4 + q) * H1);
            const float4 wb = *reinterpret_cast<const float4*>(W1 + (size_t)(k * 4 + q) * H1 + 4);
            accM[0] += xv * wa.x; accM[1] += xv * wa.y;
            accM[2] += xv * wa.z; accM[3] += xv * wa.w;
            accM[4] += xv * wb.x; accM[5] += xv * wb.y;
            accM[6] += xv * wb.z; accM[7] += xv * wb.w;
        }
    }
    proj[v] = accP;
    float4* a4 = reinterpret_cast<float4*>(A + (size_t)v * H1);
    a4[0] = make_float4(accM[0], accM[1], accM[2], accM[3]);
    a4[1] = make_float4(accM[4], accM[5], accM[6], accM[7]);
}

// Per-edge argmax/argmin of proj (first occurrence wins) + direct ELL place.
__global__ __launch_bounds__(256) void k_place(const int* __restrict__ E,
                                               const float* __restrict__ proj,
                                               int* __restrict__ fill,
                                               int* __restrict__ ell) {
    int e = blockIdx.x * 256 + threadIdx.x;
    if (e >= NE) return;
    const int* er = E + (size_t)e * KE;
    int4 e0 = *reinterpret_cast<const int4*>(er);
    int4 e1 = *reinterpret_cast<const int4*>(er + 4);
    int ids[KE] = {e0.x, e0.y, e0.z, e0.w, e1.x, e1.y, e1.z, e1.w};
    float p[KE];
#pragma unroll
    for (int j = 0; j < KE; ++j) p[j] = proj[ids[j]];
    float bestMax = p[0], bestMin = p[0];
    int idMax = ids[0], idMin = ids[0];
#pragma unroll
    for (int j = 1; j < KE; ++j) {
        if (p[j] > bestMax) { bestMax = p[j]; idMax = ids[j]; }
        if (p[j] < bestMin) { bestMin = p[j]; idMin = ids[j]; }
    }
    // claim both slots first (ILP), then the dependent stores
    int ps = atomicAdd(fill + idMax, 1);
    int pi = atomicAdd(fill + idMin, 1);
    ell[(size_t)idMax * EW + ps] = idMin;
    ell[(size_t)idMin * EW + pi] = idMax;
}

// dinv[v] = rsqrt(1 + cnt/8); A *= dinv  (M1' = dinv * M1)
__global__ __launch_bounds__(256) void k_seed(const int* __restrict__ fill,
                                              float* __restrict__ dinv,
                                              float* __restrict__ A) {
    int v = blockIdx.x * 256 + threadIdx.x;
    if (v >= VN) return;
    float di = rsqrtf(1.0f + 0.125f * (float)fill[v]);
    dinv[v] = di;
    float4* ar = reinterpret_cast<float4*>(A + (size_t)v * H1);
    float4 a0 = ar[0], a1 = ar[1];
    ar[0] = make_float4(di * a0.x, di * a0.y, di * a0.z, di * a0.w);
    ar[1] = make_float4(di * a1.x, di * a1.y, di * a1.z, di * a1.w);
}

// Gather SpMM (ELL) + bias + ReLU + tiny matmul; Min rows RSI floats.
// Y[v] = dinv[v]*(M'[v] + 0.125*sum_c M'[c]);  Mout = dinv * (relu(Y+b) @ W)
template <int FIN, int FOUT, int RSI, int RSO>
__global__ __launch_bounds__(256) void k_glayer(const int* __restrict__ ell,
                                                const int* __restrict__ fill,
                                                const float* __restrict__ dinv,
                                                const float* __restrict__ bias,
                                                const float* __restrict__ W,
                                                const float* __restrict__ Min,
                                                float* __restrict__ Mout) {
    int v = blockIdx.x * 256 + threadIdx.x;
    if (v >= VN) return;
    float own[FIN], s[FIN];
    const float4* mr = reinterpret_cast<const float4*>(Min + (size_t)v * RSI);
#pragma unroll
    for (int j = 0; j < FIN / 4; ++j) {
        float4 t = mr[j];
        own[4 * j] = t.x; own[4 * j + 1] = t.y;
        own[4 * j + 2] = t.z; own[4 * j + 3] = t.w;
    }
#pragma unroll
    for (int j = 0; j < FIN; ++j) s[j] = 0.f;
    int deg = fill[v];
    const int* row = ell + (size_t)v * EW;
    int base = 0;
    // chunk-of-4 pipelined gather: one int4 index load, 4 rows in flight
    for (; base + 4 <= deg; base += 4) {
        int4 c4 = *reinterpret_cast<const int4*>(row + base);
        const float4* r0 = reinterpret_cast<const float4*>(Min + (size_t)c4.x * RSI);
        const float4* r1 = reinterpret_cast<const float4*>(Min + (size_t)c4.y * RSI);
        const float4* r2 = reinterpret_cast<const float4*>(Min + (size_t)c4.z * RSI);
        const float4* r3 = reinterpret_cast<const float4*>(Min + (size_t)c4.w * RSI);
        float4 t0[FIN / 4], t1[FIN / 4], t2[FIN / 4], t3[FIN / 4];
#pragma unroll
        for (int j = 0; j < FIN / 4; ++j) t0[j] = r0[j];
#pragma unroll
        for (int j = 0; j < FIN / 4; ++j) t1[j] = r1[j];
#pragma unroll
        for (int j = 0; j < FIN / 4; ++j) t2[j] = r2[j];
#pragma unroll
        for (int j = 0; j < FIN / 4; ++j) t3[j] = r3[j];
#pragma unroll
        for (int j = 0; j < FIN / 4; ++j) {
            s[4 * j]     += t0[j].x + t1[j].x + t2[j].x + t3[j].x;
            s[4 * j + 1] += t0[j].y + t1[j].y + t2[j].y + t3[j].y;
            s[4 * j + 2] += t0[j].z + t1[j].z + t2[j].z + t3[j].z;
            s[4 * j + 3] += t0[j].w + t1[j].w + t2[j].w + t3[j].w;
        }
    }
    for (; base < deg; ++base) {
        int c = row[base];
        const float4* cr = reinterpret_cast<const float4*>(Min + (size_t)c * RSI);
#pragma unroll
        for (int j = 0; j < FIN / 4; ++j) {
            float4 t = cr[j];
            s[4 * j] += t.x; s[4 * j + 1] += t.y;
            s[4 * j + 2] += t.z; s[4 * j + 3] += t.w;
        }
    }
    float di = dinv[v];
    float h[FIN];
#pragma unroll
    for (int j = 0; j < FIN; ++j) {
        float y = di * (own[j] + 0.125f * s[j]) + bias[j];
        h[j] = y > 0.f ? y : 0.f;
    }
#pragma unroll
    for (int c = 0; c < FOUT; ++c) {
        float m = 0.f;
#pragma unroll
        for (int j = 0; j < FIN; ++j) m += h[j] * W[j * FOUT + c];
        Mout[(size_t)v * RSO + c] = di * m;
    }
}

// Final: gather Y3 (RS=16), relu(Y3+b3), dot fc_w, sigmoid
__global__ __launch_bounds__(256) void k_gfinal(const int* __restrict__ ell,
                                                const int* __restrict__ fill,
                                                const float* __restrict__ dinv,
                                                const float* __restrict__ b3,
                                                const float* __restrict__ fcw,
                                                const float* __restrict__ fcb,
                                                const float* __restrict__ Min,
                                                float* __restrict__ out) {
    int v = blockIdx.x * 256 + threadIdx.x;
    if (v >= VN) return;
    float own[CC], s[CC];
    const float4* mr = reinterpret_cast<const float4*>(Min + (size_t)v * CC);
#pragma unroll
    for (int j = 0; j < CC / 4; ++j) {
        float4 t = mr[j];
        own[4 * j] = t.x; own[4 * j + 1] = t.y;
        own[4 * j + 2] = t.z; own[4 * j + 3] = t.w;
    }
#pragma unroll
    for (int j = 0; j < CC; ++j) s[j] = 0.f;
    int deg = fill[v];
    const int* row = ell + (size_t)v * EW;
    int base = 0;
    for (; base + 2 <= deg; base += 2) {
        int c0 = row[base], c1 = row[base + 1];
        const float4* r0 = reinterpret_cast<const float4*>(Min + (size_t)c0 * CC);
        const float4* r1 = reinterpret_cast<const float4*>(Min + (size_t)c1 * CC);
        float4 t0[CC / 4], t1[CC / 4];
#pragma unroll
        for (int j = 0; j < CC / 4; ++j) t0[j] = r0[j];
#pragma unroll
        for (int j = 0; j < CC / 4; ++j) t1[j] = r1[j];
#pragma unroll
        for (int j = 0; j < CC / 4; ++j) {
            s[4 * j]     += t0[j].x + t1[j].x;
            s[4 * j + 1] += t0[j].y + t1[j].y;
            s[4 * j + 2] += t0[j].z + t1[j].z;
            s[4 * j + 3] += t0[j].w + t1[j].w;
        }
    }
    if (base < deg) {
        int c = row[base];
        const float4* cr = reinterpret_cast<const float4*>(Min + (size_t)c * CC);
#pragma unroll
        for (int j = 0; j < CC / 4; ++j) {
            float4 t = cr[j];
            s[4 * j] += t.x; s[4 * j + 1] += t.y;
            s[4 * j + 2] += t.z; s[4 * j + 3] += t.w;
        }
    }
    float di = dinv[v];
    float acc = fcb[0];
#pragma unroll
    for (int j = 0; j < CC; ++j) {
        float y = di * (own[j] + 0.125f * s[j]) + b3[j];
        float hh = y > 0.f ? y : 0.f;
        acc += hh * fcw[j];
    }
    out[v] = 1.f / (1.f + expf(-acc));
}

extern "C" void kernel_launch(void* const* d_in, const int* in_sizes, int n_in,
                              void* d_out, int out_size, void* d_ws, size_t ws_size,
                              hipStream_t stream) {
    const float* X   = (const float*)d_in[0];
    const int*   E   = (const int*)d_in[1];
    const float* rv  = (const float*)d_in[2];
    const float* W1  = (const float*)d_in[3];
    const float* b1  = (const float*)d_in[4];
    const float* W2  = (const float*)d_in[5];
    const float* b2  = (const float*)d_in[6];
    const float* W3  = (const float*)d_in[7];
    const float* b3  = (const float*)d_in[8];
    const float* fcw = (const float*)d_in[9];
    const float* fcb = (const float*)d_in[10];
    float* out = (float*)d_out;

    float* ws = (float*)d_ws;
    float* A    = ws;                          // [VN x 8]  16 MB (M1')
    float* B    = ws + 4000000;                // [VN x 8]  16 MB (M2')
    float* C    = ws + 8000000;                // [VN x 16] 32 MB (M3')
    float* proj = ws + 16000000;               // [VN]
    float* dinv = ws + 16500000;               // [VN]
    int*   fill = (int*)(ws + 17000000);       // [VN] slot counters == cnt
    int*   ell  = (int*)(ws + 17500000);       // [VN x 64] 128 MB

    dim3 blk(256);
    int gV = (VN + 255) / 256;
    int gE = (NE + 255) / 256;

    k_row<<<gV, blk, 0, stream>>>(X, rv, W1, proj, A, fill);
    k_place<<<gE, blk, 0, stream>>>(E, proj, fill, ell);
    k_seed<<<gV, blk, 0, stream>>>(fill, dinv, A);

    // layer 1: A(M1',RS8) -> B(M2',RS8)
    k_glayer<8, 8, 8, 8><<<gV, blk, 0, stream>>>(ell, fill, dinv, b1, W2, A, B);
    // layer 2: B(M2',RS8) -> C(M3',RS16)
    k_glayer<8, 16, 8, 16><<<gV, blk, 0, stream>>>(ell, fill, dinv, b2, W3, B, C);
    // layer 3 + head: C(M3',RS16) -> out
    k_gfinal<<<gV, blk, 0, stream>>>(ell, fill, dinv, b3, fcw, fcb, C, out);
}